// Round 1
// baseline (1117.945 us; speedup 1.0000x reference)
//
#include <hip/hip_runtime.h>
#include <hip/hip_bf16.h>

#define BB 8
#define NQ 2048
#define NKK 2048
#define DD 1024

typedef __attribute__((ext_vector_type(8))) short short8;
typedef __attribute__((ext_vector_type(4))) short short4v;
typedef __attribute__((ext_vector_type(4))) float f32x4;

static __device__ __forceinline__ unsigned short f2b(float f) {
  __hip_bfloat16 h = __float2bfloat16(f);
  return __builtin_bit_cast(unsigned short, h);
}
static __device__ __forceinline__ float b2f(unsigned short u) {
  return __bfloat162float(__builtin_bit_cast(__hip_bfloat16, u));
}

typedef const __attribute__((address_space(1))) unsigned short GUS;
typedef __attribute__((address_space(3))) unsigned short LUS;
static __device__ __forceinline__ void gload16(const unsigned short* g, unsigned short* l) {
  __builtin_amdgcn_global_load_lds((GUS*)g, (LUS*)l, 16, 0, 0);
}

// ---------------- cast f32 -> bf16 (8 elems/thread) ----------------
__global__ __launch_bounds__(256) void cast_bf16_k(const float* __restrict__ in,
                                                   unsigned short* __restrict__ out) {
  size_t idx = ((size_t)blockIdx.x * 256 + threadIdx.x) * 8;
  f32x4 a = *reinterpret_cast<const f32x4*>(in + idx);
  f32x4 b = *reinterpret_cast<const f32x4*>(in + idx + 4);
  short8 o;
  o[0] = (short)f2b(a[0]); o[1] = (short)f2b(a[1]);
  o[2] = (short)f2b(a[2]); o[3] = (short)f2b(a[3]);
  o[4] = (short)f2b(b[0]); o[5] = (short)f2b(b[1]);
  o[6] = (short)f2b(b[2]); o[7] = (short)f2b(b[3]);
  *reinterpret_cast<short8*>(out + idx) = o;
}

// ---------------- W[k][n] f32 -> Wt[n][k] bf16 (1024x1024) ----------------
__global__ __launch_bounds__(256) void transpose_cast_k(const float* __restrict__ W,
                                                        unsigned short* __restrict__ Wt) {
  __shared__ float tile[32][33];
  int bx = blockIdx.x * 32, by = blockIdx.y * 32;
  int tx = threadIdx.x & 31;
  int ty = threadIdx.x >> 5;  // 0..7
#pragma unroll
  for (int i = 0; i < 4; i++)
    tile[ty + i * 8][tx] = W[(size_t)(by + ty + i * 8) * DD + bx + tx];
  __syncthreads();
#pragma unroll
  for (int i = 0; i < 4; i++)
    Wt[(size_t)(bx + ty + i * 8) * DD + by + tx] = f2b(tile[tx][ty + i * 8]);
}

// ---------------- GEMM: C = A[M,K] * Bt[N,K]^T (+bias)*scale ----------------
// CMODE 0: f32 out ; 1: bf16 out ; 2: bf16 transposed out (C[n][m])
template <int CMODE>
__global__ __launch_bounds__(256) void gemm_bt(
    const unsigned short* __restrict__ A, const unsigned short* __restrict__ Bt,
    const float* __restrict__ bias, void* __restrict__ C,
    int M, int N, int K, long long sA, long long sB, long long sC, float scale) {
  __shared__ unsigned short As[128 * 64];
  __shared__ unsigned short Bs[128 * 64];
  const int tid = threadIdx.x;
  const int lane = tid & 63;
  const int w = tid >> 6;
  const int bz = blockIdx.z;
  const int m0 = blockIdx.y * 128;
  const int n0 = blockIdx.x * 128;
  const unsigned short* Ab = A + (size_t)bz * sA;
  const unsigned short* Btb = Bt + (size_t)bz * sB;

  f32x4 acc[4][4] = {};

  const int wm = (w >> 1) * 64;
  const int wn = (w & 1) * 64;
  const int fr = lane & 15;
  const int fk = (lane >> 4) * 8;

  for (int k0 = 0; k0 < K; k0 += 64) {
#pragma unroll
    for (int i = 0; i < 4; i++) {
      int flat = (i * 256 + tid) * 8;  // element index within 128x64 tile
      int row = flat >> 6;
      int col = flat & 63;
      gload16(Ab + (size_t)(m0 + row) * K + k0 + col, &As[flat]);
      gload16(Btb + (size_t)(n0 + row) * K + k0 + col, &Bs[flat]);
    }
    __syncthreads();
#pragma unroll
    for (int kk = 0; kk < 64; kk += 32) {
      short8 af[4], bfr[4];
#pragma unroll
      for (int i = 0; i < 4; i++)
        af[i] = *reinterpret_cast<const short8*>(&As[(wm + i * 16 + fr) * 64 + kk + fk]);
#pragma unroll
      for (int j = 0; j < 4; j++)
        bfr[j] = *reinterpret_cast<const short8*>(&Bs[(wn + j * 16 + fr) * 64 + kk + fk]);
#pragma unroll
      for (int i = 0; i < 4; i++)
#pragma unroll
        for (int j = 0; j < 4; j++)
          acc[i][j] = __builtin_amdgcn_mfma_f32_16x16x32_bf16(af[i], bfr[j], acc[i][j], 0, 0, 0);
    }
    __syncthreads();
  }

  const int cr = (lane >> 4) * 4;
  const int cc = lane & 15;
#pragma unroll
  for (int i = 0; i < 4; i++) {
#pragma unroll
    for (int j = 0; j < 4; j++) {
      int col = n0 + wn + j * 16 + cc;
      float bv_ = bias ? bias[col] : 0.0f;
#pragma unroll
      for (int r = 0; r < 4; r++) {
        int row = m0 + wm + i * 16 + cr + r;
        float v = (acc[i][j][r] + bv_) * scale;
        if (CMODE == 0) {
          ((float*)C)[(size_t)bz * sC + (size_t)row * N + col] = v;
        } else if (CMODE == 1) {
          ((unsigned short*)C)[(size_t)bz * sC + (size_t)row * N + col] = f2b(v);
        } else {
          ((unsigned short*)C)[(size_t)bz * sC + (size_t)col * M + row] = f2b(v);
        }
      }
    }
  }
}

// ---------------- masked row softmax: f32 scores -> bf16 probs ----------------
__global__ __launch_bounds__(256) void softmax_mask_k(const float* __restrict__ S,
                                                      const int* __restrict__ mask,
                                                      unsigned short* __restrict__ P,
                                                      int b_off) {
  __shared__ float red1[4], red2[4];
  int r = blockIdx.x;
  int b = b_off + (r >> 11);  // 2048 rows / batch
  const float* Srow = S + (size_t)r * NKK;
  const int* mrow = mask + (size_t)b * NKK;
  int tid = threadIdx.x;
  float vals[8];
  float mx = -INFINITY;
#pragma unroll
  for (int i = 0; i < 8; i++) {
    int c = tid + i * 256;
    float s = Srow[c];
    s = (mrow[c] == 0) ? -1e9f : s;
    vals[i] = s;
    mx = fmaxf(mx, s);
  }
#pragma unroll
  for (int o = 32; o; o >>= 1) mx = fmaxf(mx, __shfl_xor(mx, o));
  int w = tid >> 6, lane = tid & 63;
  if (lane == 0) red1[w] = mx;
  __syncthreads();
  mx = fmaxf(fmaxf(red1[0], red1[1]), fmaxf(red1[2], red1[3]));
  float sum = 0.0f;
#pragma unroll
  for (int i = 0; i < 8; i++) {
    vals[i] = __expf(vals[i] - mx);
    sum += vals[i];
  }
#pragma unroll
  for (int o = 32; o; o >>= 1) sum += __shfl_xor(sum, o);
  if (lane == 0) red2[w] = sum;
  __syncthreads();
  sum = red2[0] + red2[1] + red2[2] + red2[3];
  float inv = 1.0f / sum;
#pragma unroll
  for (int i = 0; i < 8; i++) {
    int c = tid + i * 256;
    P[(size_t)r * NKK + c] = f2b(vals[i] * inv);
  }
}

// ---------------- LayerNorm: bf16 [rows,1024] -> f32 out ----------------
__global__ __launch_bounds__(256) void ln_k(const unsigned short* __restrict__ X,
                                            const float* __restrict__ g,
                                            const float* __restrict__ be,
                                            float* __restrict__ out) {
  __shared__ float r1[4], r2[4];
  int r = blockIdx.x, tid = threadIdx.x;
  const unsigned short* xr = X + (size_t)r * DD;
  short4v xv = *reinterpret_cast<const short4v*>(xr + tid * 4);
  float x[4];
#pragma unroll
  for (int i = 0; i < 4; i++) x[i] = b2f((unsigned short)xv[i]);
  float s = x[0] + x[1] + x[2] + x[3];
#pragma unroll
  for (int o = 32; o; o >>= 1) s += __shfl_xor(s, o);
  int w = tid >> 6, lane = tid & 63;
  if (lane == 0) r1[w] = s;
  __syncthreads();
  float mu = (r1[0] + r1[1] + r1[2] + r1[3]) * (1.0f / DD);
  float d[4];
#pragma unroll
  for (int i = 0; i < 4; i++) d[i] = x[i] - mu;
  float sq = d[0] * d[0] + d[1] * d[1] + d[2] * d[2] + d[3] * d[3];
#pragma unroll
  for (int o = 32; o; o >>= 1) sq += __shfl_xor(sq, o);
  if (lane == 0) r2[w] = sq;
  __syncthreads();
  float var = (r2[0] + r2[1] + r2[2] + r2[3]) * (1.0f / DD);
  float rs = rsqrtf(var + 1e-5f);
  int c = tid * 4;
  f32x4 ov;
#pragma unroll
  for (int i = 0; i < 4; i++) ov[i] = d[i] * rs * g[c + i] + be[c + i];
  *reinterpret_cast<f32x4*>(out + (size_t)r * DD + c) = ov;
}

extern "C" void kernel_launch(void* const* d_in, const int* in_sizes, int n_in,
                              void* d_out, int out_size, void* d_ws, size_t ws_size,
                              hipStream_t stream) {
  const float* Qf = (const float*)d_in[0];
  const float* Kf = (const float*)d_in[1];
  const float* Vf = (const float*)d_in[2];
  const int* pad = (const int*)d_in[3];
  const float* Wq = (const float*)d_in[4];
  const float* bq = (const float*)d_in[5];
  const float* Wk = (const float*)d_in[6];
  const float* bk = (const float*)d_in[7];
  const float* Wv = (const float*)d_in[8];
  const float* bv = (const float*)d_in[9];
  const float* Wo = (const float*)d_in[10];
  const float* bo = (const float*)d_in[11];
  const float* g0 = (const float*)d_in[12];
  const float* be0 = (const float*)d_in[13];
  float* out = (float*)d_out;

  const size_t MT = (size_t)BB * NQ;  // 16384
  const size_t EL = MT * DD;          // 16.7M elems

  char* ws = (char*)d_ws;
  size_t off = 0;
  auto alloc = [&](size_t b) {
    char* p = ws + off;
    off += (b + 255) & ~(size_t)255;
    return p;
  };
  unsigned short* Xq = (unsigned short*)alloc(EL * 2);
  unsigned short* Xk = (unsigned short*)alloc(EL * 2);
  unsigned short* Xv = (unsigned short*)alloc(EL * 2);
  unsigned short* WqT = (unsigned short*)alloc((size_t)DD * DD * 2);
  unsigned short* WkT = (unsigned short*)alloc((size_t)DD * DD * 2);
  unsigned short* WvT = (unsigned short*)alloc((size_t)DD * DD * 2);
  unsigned short* WoT = (unsigned short*)alloc((size_t)DD * DD * 2);
  unsigned short* qb = (unsigned short*)alloc(EL * 2);
  unsigned short* kb = (unsigned short*)alloc(EL * 2);
  unsigned short* vT = (unsigned short*)alloc(EL * 2);
  unsigned short* attnout = Xk;  // reuse (Xk dead after kb)
  unsigned short* projout = Xq;  // reuse (Xq dead after qb)

  size_t scores_full = (size_t)BB * NQ * NKK * 4;
  size_t p_full = (size_t)BB * NQ * NKK * 2;
  int zc = (ws_size >= off + scores_full + p_full + 4096) ? BB : 1;
  float* Sbuf = (float*)alloc((size_t)zc * NQ * NKK * 4);
  unsigned short* Pbuf = (unsigned short*)alloc((size_t)zc * NQ * NKK * 2);

  // casts
  cast_bf16_k<<<EL / 2048, 256, 0, stream>>>(Qf, Xq);
  cast_bf16_k<<<EL / 2048, 256, 0, stream>>>(Kf, Xk);
  cast_bf16_k<<<EL / 2048, 256, 0, stream>>>(Vf, Xv);
  dim3 tg(DD / 32, DD / 32);
  transpose_cast_k<<<tg, 256, 0, stream>>>(Wq, WqT);
  transpose_cast_k<<<tg, 256, 0, stream>>>(Wk, WkT);
  transpose_cast_k<<<tg, 256, 0, stream>>>(Wv, WvT);
  transpose_cast_k<<<tg, 256, 0, stream>>>(Wo, WoT);

  const long long sAb = (long long)NQ * DD;  // 2048*1024 per-batch stride

  // projections (scale 1/sqrt(1024) folded into q, exact pow2)
  dim3 gp(DD / 128, NQ / 128, BB);
  gemm_bt<1><<<gp, 256, 0, stream>>>(Xq, WqT, bq, qb, NQ, DD, DD, sAb, 0, sAb, 0.03125f);
  gemm_bt<1><<<gp, 256, 0, stream>>>(Xk, WkT, bk, kb, NQ, DD, DD, sAb, 0, sAb, 1.0f);
  gemm_bt<2><<<gp, 256, 0, stream>>>(Xv, WvT, bv, vT, NQ, DD, DD, sAb, 0, sAb, 1.0f);

  for (int b0 = 0; b0 < BB; b0 += zc) {
    dim3 gs(NKK / 128, NQ / 128, zc);
    gemm_bt<0><<<gs, 256, 0, stream>>>(qb + (size_t)b0 * sAb, kb + (size_t)b0 * sAb, nullptr,
                                       Sbuf, NQ, NKK, DD, sAb, sAb, (long long)NQ * NKK, 1.0f);
    softmax_mask_k<<<zc * NQ, 256, 0, stream>>>(Sbuf, pad, Pbuf, b0);
    dim3 gv(DD / 128, NQ / 128, zc);
    gemm_bt<1><<<gv, 256, 0, stream>>>(Pbuf, vT + (size_t)b0 * sAb, nullptr,
                                       attnout + (size_t)b0 * sAb, NQ, DD, NKK,
                                       (long long)NQ * NKK, sAb, sAb, 1.0f);
  }

  // output projection + layernorm
  gemm_bt<1><<<gp, 256, 0, stream>>>(attnout, WoT, bo, projout, NQ, DD, DD, sAb, 0, sAb, 1.0f);
  ln_k<<<MT, 256, 0, stream>>>(projout, g0, be0, out);
}